// Round 1
// baseline (9138.585 us; speedup 1.0000x reference)
//
#include <hip/hip_runtime.h>

// LSTM_3813930958978: T=512, B=64, I=1024, H=1024, gate order i,f,g,o.
// Strategy: persistent cooperative kernel, 128 blocks x 256 threads.
// Block k owns h-columns [8k, 8k+8) => 32 gate columns.
// Weights held in registers as MFMA B-fragments (K split over 4 waves).
// Per step: gates[64x32] = x_t @ W_ih^T + h @ W_hh^T (fused, bf16 MFMA,
// fp32 accum) -> cross-wave LDS reduction -> elementwise -> h bf16 store
// -> device-wide barrier (monotonic counter, device-scope atomics).

#define TT 512
#define BB 64
#define II 1024
#define HHH 1024
#define G4 4096
#define NBLK 128
#define HPB 8

typedef __attribute__((ext_vector_type(8))) short short8;
typedef __attribute__((ext_vector_type(4))) float f32x4;
typedef __attribute__((ext_vector_type(4))) int i32x4;

__device__ __forceinline__ short8 load_frag(const unsigned short* p) {
  i32x4 v = *(const i32x4*)p;
  return __builtin_bit_cast(short8, v);
}

__device__ __forceinline__ unsigned short f2bf(float f) {
  unsigned u = __builtin_bit_cast(unsigned, f);
  u = (u + 0x7FFFu + ((u >> 16) & 1u)) >> 16;
  return (unsigned short)u;
}

__device__ __forceinline__ float sigm(float x) {
  return 1.0f / (1.0f + __expf(-x));
}
__device__ __forceinline__ float tanh_f(float x) {
  return 2.0f / (1.0f + __expf(-2.0f * x)) - 1.0f;
}

// ---- conversion kernels ------------------------------------------------
__global__ void cvt_bf16(const float* __restrict__ s,
                         unsigned short* __restrict__ d, int n4) {
  int stride = gridDim.x * blockDim.x;
  for (int i = blockIdx.x * blockDim.x + threadIdx.x; i < n4; i += stride) {
    f32x4 v = *(const f32x4*)(s + 4 * i);
    unsigned lo = (unsigned)f2bf(v[0]) | ((unsigned)f2bf(v[1]) << 16);
    unsigned hi = (unsigned)f2bf(v[2]) | ((unsigned)f2bf(v[3]) << 16);
    uint2 u; u.x = lo; u.y = hi;
    *(uint2*)(d + 4 * i) = u;
  }
}

__global__ void bias_sum(const float* __restrict__ a,
                         const float* __restrict__ b,
                         float* __restrict__ o) {
  int i = blockIdx.x * blockDim.x + threadIdx.x;
  if (i < G4) o[i] = a[i] + b[i];
}

// ---- persistent LSTM kernel -------------------------------------------
__global__ __launch_bounds__(256, 1) void lstm_persist(
    const unsigned short* __restrict__ xb,    // [T][64][1024] bf16
    const unsigned short* __restrict__ wih,   // [4096][1024] bf16
    const unsigned short* __restrict__ whh,   // [4096][1024] bf16
    const float* __restrict__ bsum,           // [4096] f32 (b_ih + b_hh)
    unsigned short* __restrict__ hbuf,        // 2 x [64][1024] bf16 (zeroed)
    unsigned int* __restrict__ bar,           // zeroed
    float* __restrict__ out)                  // [64][1024] f32
{
  const int tid = threadIdx.x;
  const int wid = tid >> 6;          // wave 0..3
  const int lane = tid & 63;
  const int ln15 = lane & 15;
  const int quad = lane >> 4;
  const int hc0 = blockIdx.x * HPB;  // this block's first h-column
  const int koff = (wid & 1) * 512;  // K-slice within the wave's matrix
  const bool isx = (wid < 2);        // waves 0,1: x part; waves 2,3: h part
  const unsigned short* wsrc = isx ? wih : whh;

  __shared__ float red[4][64][33];   // per-wave partial gate tiles (padded)

  // ---- load persistent B fragments (weights) --------------------------
  // B[k][n] = W[gate_row(n)][k];  n = q*8 + r -> gate_row = q*1024 + hc0 + r
  short8 bfrag[16][2];
#pragma unroll
  for (int nt = 0; nt < 2; ++nt) {
    int n = nt * 16 + ln15;
    int grow = (n >> 3) * 1024 + hc0 + (n & 7);
#pragma unroll
    for (int kc = 0; kc < 16; ++kc) {
      int k = koff + kc * 32 + quad * 8;
      bfrag[kc][nt] = load_frag(wsrc + grow * 1024 + k);
    }
  }

  // ---- elementwise-phase constants ------------------------------------
  const int eb = tid >> 2;   // batch row handled in elementwise phase
  const int erp = tid & 3;   // r-pair: handles r = 2*erp, 2*erp+1
  float bsv[4][2];
#pragma unroll
  for (int q = 0; q < 4; ++q)
#pragma unroll
    for (int rr = 0; rr < 2; ++rr)
      bsv[q][rr] = bsum[q * 1024 + hc0 + erp * 2 + rr];

  float cst[2] = {0.0f, 0.0f};  // c-state, fp32, lives in registers

#pragma unroll 1
  for (int t = 0; t < TT; ++t) {
    const unsigned short* hsrc = hbuf + (t & 1) * (BB * HHH);
    unsigned short* hdst = hbuf + ((t + 1) & 1) * (BB * HHH);
    const unsigned short* asrc = isx ? (xb + t * (BB * II)) : hsrc;

    f32x4 acc[4][2];
#pragma unroll
    for (int m = 0; m < 4; ++m)
#pragma unroll
      for (int nt = 0; nt < 2; ++nt)
        acc[m][nt] = (f32x4){0.0f, 0.0f, 0.0f, 0.0f};

    // ---- MFMA over this wave's K slice --------------------------------
#pragma unroll
    for (int kc = 0; kc < 16; ++kc) {
      int k = koff + kc * 32 + quad * 8;
#pragma unroll
      for (int m = 0; m < 4; ++m) {
        short8 a = load_frag(asrc + (m * 16 + ln15) * 1024 + k);
        acc[m][0] = __builtin_amdgcn_mfma_f32_16x16x32_bf16(
            a, bfrag[kc][0], acc[m][0], 0, 0, 0);
        acc[m][1] = __builtin_amdgcn_mfma_f32_16x16x32_bf16(
            a, bfrag[kc][1], acc[m][1], 0, 0, 0);
      }
    }

    // ---- dump partials to LDS (D layout: row=(quad*4+p), col=ln15) ----
#pragma unroll
    for (int m = 0; m < 4; ++m)
#pragma unroll
      for (int nt = 0; nt < 2; ++nt)
#pragma unroll
        for (int p = 0; p < 4; ++p)
          red[wid][m * 16 + quad * 4 + p][nt * 16 + ln15] = acc[m][nt][p];

    __syncthreads();

    // ---- reduce 4 waves + bias, gate nonlinearities, state update -----
    float hv[2];
#pragma unroll
    for (int rr = 0; rr < 2; ++rr) {
      int r = erp * 2 + rr;
      float g[4];
#pragma unroll
      for (int q = 0; q < 4; ++q) {
        int col = q * 8 + r;
        g[q] = red[0][eb][col] + red[1][eb][col] + red[2][eb][col] +
               red[3][eb][col] + bsv[q][rr];
      }
      float ig = sigm(g[0]);
      float fg = sigm(g[1]);
      float gg = tanh_f(g[2]);
      float og = sigm(g[3]);
      float c = fg * cst[rr] + ig * gg;
      cst[rr] = c;
      hv[rr] = og * tanh_f(c);
    }
    unsigned hpack = (unsigned)f2bf(hv[0]) | ((unsigned)f2bf(hv[1]) << 16);
    *(unsigned*)(hdst + eb * HHH + hc0 + erp * 2) = hpack;

    if (t == TT - 1) {
      float2 o2; o2.x = hv[0]; o2.y = hv[1];
      *(float2*)(out + eb * HHH + hc0 + erp * 2) = o2;
    }

    // ---- device-wide barrier ------------------------------------------
    __syncthreads();  // drains all waves' h stores (vmcnt(0) before s_barrier)
    if (tid == 0) {
      __threadfence();             // release: flush h writes to LLC
      atomicAdd(bar, 1u);
      unsigned tgt = (unsigned)(t + 1) * NBLK;
      while (__hip_atomic_load(bar, __ATOMIC_RELAXED,
                               __HIP_MEMORY_SCOPE_AGENT) < tgt) { }
      __threadfence();             // acquire: invalidate stale L1/L2 lines
    }
    __syncthreads();
  }
}

// ---- launcher ----------------------------------------------------------
extern "C" void kernel_launch(void* const* d_in, const int* in_sizes, int n_in,
                              void* d_out, int out_size, void* d_ws,
                              size_t ws_size, hipStream_t stream) {
  (void)in_sizes; (void)n_in; (void)out_size; (void)ws_size;
  const float* x   = (const float*)d_in[0];
  const float* wih = (const float*)d_in[1];
  const float* whh = (const float*)d_in[2];
  const float* bih = (const float*)d_in[3];
  const float* bhh = (const float*)d_in[4];

  char* ws = (char*)d_ws;
  // workspace layout (bytes):
  //   [0,256)            barrier counter
  //   [256, 256+256KiB)  h double buffer (2 x 64x1024 bf16)
  //   [1MiB, 9MiB)       W_ih bf16
  //   [9MiB, 17MiB)      W_hh bf16
  //   [17MiB, +16KiB)    bias sum f32
  //   [18MiB, 82MiB)     x bf16
  unsigned int*  bar  = (unsigned int*)(ws);
  unsigned short* hb  = (unsigned short*)(ws + 256);
  unsigned short* wihb = (unsigned short*)(ws + (1ull << 20));
  unsigned short* whhb = (unsigned short*)(ws + (9ull << 20));
  float*          bs   = (float*)(ws + (17ull << 20));
  unsigned short* xb   = (unsigned short*)(ws + (18ull << 20));

  // zero barrier + h buffers (ws is poisoned 0xAA before every launch)
  hipMemsetAsync(ws, 0, 256 + 2ull * BB * HHH * sizeof(unsigned short), stream);

  cvt_bf16<<<2048, 256, 0, stream>>>(x, xb, (TT * BB * II) / 4);
  cvt_bf16<<<1024, 256, 0, stream>>>(wih, wihb, (G4 * II) / 4);
  cvt_bf16<<<1024, 256, 0, stream>>>(whh, whhb, (G4 * HHH) / 4);
  bias_sum<<<16, 256, 0, stream>>>(bih, bhh, bs);

  lstm_persist<<<NBLK, 256, 0, stream>>>(xb, wihb, whhb, bs, hb, bar,
                                         (float*)d_out);
}

// Round 2
// 8643.630 us; speedup vs baseline: 1.0573x; 1.0573x over previous
//
#include <hip/hip_runtime.h>

// LSTM_3813930958978: T=512, B=64, I=1024, H=1024, gate order i,f,g,o.
// Persistent cooperative kernel, 128 blocks x 256 threads (1 block/CU).
// Block k owns h-columns [8k, 8k+8) => 32 gate columns.
// Weights live in registers as MFMA B-fragments (K split over 2 waves per
// matrix). Waves 0,1 compute x_t @ W_ih^T (never wait on the global
// barrier); waves 2,3 poll the epoch word, then compute h @ W_hh^T.
// Barrier = 2-level arrival tree (8 leaf lines x16 blocks -> root x8) +
// single-writer epoch broadcast word polled read-only with s_sleep backoff.

#define TT 512
#define BB 64
#define II 1024
#define HHH 1024
#define G4 4096
#define NBLK 128
#define HPB 8

typedef __attribute__((ext_vector_type(8))) short short8;
typedef __attribute__((ext_vector_type(4))) float f32x4;
typedef __attribute__((ext_vector_type(4))) int i32x4;

__device__ __forceinline__ short8 load_frag(const unsigned short* p) {
  i32x4 v = *(const i32x4*)p;
  return __builtin_bit_cast(short8, v);
}

__device__ __forceinline__ unsigned short f2bf(float f) {
  unsigned u = __builtin_bit_cast(unsigned, f);
  u = (u + 0x7FFFu + ((u >> 16) & 1u)) >> 16;
  return (unsigned short)u;
}

__device__ __forceinline__ float sigm(float x) {
  return 1.0f / (1.0f + __expf(-x));
}
__device__ __forceinline__ float tanh_f(float x) {
  return 2.0f / (1.0f + __expf(-2.0f * x)) - 1.0f;
}

// ---- conversion kernels ------------------------------------------------
__global__ void cvt_bf16(const float* __restrict__ s,
                         unsigned short* __restrict__ d, int n4) {
  int stride = gridDim.x * blockDim.x;
  for (int i = blockIdx.x * blockDim.x + threadIdx.x; i < n4; i += stride) {
    f32x4 v = *(const f32x4*)(s + 4 * i);
    unsigned lo = (unsigned)f2bf(v[0]) | ((unsigned)f2bf(v[1]) << 16);
    unsigned hi = (unsigned)f2bf(v[2]) | ((unsigned)f2bf(v[3]) << 16);
    uint2 u; u.x = lo; u.y = hi;
    *(uint2*)(d + 4 * i) = u;
  }
}

__global__ void bias_sum(const float* __restrict__ a,
                         const float* __restrict__ b,
                         float* __restrict__ o) {
  int i = blockIdx.x * blockDim.x + threadIdx.x;
  if (i < G4) o[i] = a[i] + b[i];
}

// ---- persistent LSTM kernel -------------------------------------------
// barrier_mem (uint words): [0]=epoch (poll target), [32]=root,
//                           [64 + 32*g]=leaf g (g=0..7). 128B line spacing.
__global__ __launch_bounds__(256, 1) void lstm_persist(
    const unsigned short* __restrict__ xb,    // [T][64][1024] bf16
    const unsigned short* __restrict__ wih,   // [4096][1024] bf16
    const unsigned short* __restrict__ whh,   // [4096][1024] bf16
    const float* __restrict__ bsum,           // [4096] f32 (b_ih + b_hh)
    unsigned short* __restrict__ hbuf,        // 2 x [64][1024] bf16 (zeroed)
    unsigned int* __restrict__ barrier_mem,   // zeroed
    float* __restrict__ out)                  // [64][1024] f32
{
  const int tid = threadIdx.x;
  const int wid = tid >> 6;          // wave 0..3
  const int lane = tid & 63;
  const int ln15 = lane & 15;
  const int quad = lane >> 4;
  const int hc0 = blockIdx.x * HPB;  // this block's first h-column
  const int koff = (wid & 1) * 512;  // K-slice within the wave's matrix
  const bool isx = (wid < 2);        // waves 0,1: x part; waves 2,3: h part
  const unsigned short* wsrc = isx ? wih : whh;

  unsigned int* epoch = barrier_mem;
  unsigned int* root = barrier_mem + 32;
  unsigned int* leaf = barrier_mem + 64 + (blockIdx.x >> 4) * 32;

  __shared__ float red[4][64][36];   // stride 36: quad offsets {0,16,0,16}
                                     // -> 2-way-only write aliasing (free)

  // ---- load persistent B fragments (weights) --------------------------
  // B[k][n] = W[gate_row(n)][k];  n = q*8 + r -> gate_row = q*1024 + hc0 + r
  short8 bfrag[16][2];
#pragma unroll
  for (int nt = 0; nt < 2; ++nt) {
    int n = nt * 16 + ln15;
    int grow = (n >> 3) * 1024 + hc0 + (n & 7);
#pragma unroll
    for (int kc = 0; kc < 16; ++kc) {
      int k = koff + kc * 32 + quad * 8;
      bfrag[kc][nt] = load_frag(wsrc + grow * 1024 + k);
    }
  }

  // ---- elementwise-phase constants ------------------------------------
  const int eb = tid >> 2;   // batch row handled in elementwise phase
  const int erp = tid & 3;   // r-pair: handles r = 2*erp, 2*erp+1
  float bsv[4][2];
#pragma unroll
  for (int q = 0; q < 4; ++q)
#pragma unroll
    for (int rr = 0; rr < 2; ++rr)
      bsv[q][rr] = bsum[q * 1024 + hc0 + erp * 2 + rr];

  float cst[2] = {0.0f, 0.0f};  // c-state, fp32, lives in registers

#pragma unroll 1
  for (int t = 0; t < TT; ++t) {
    const unsigned short* hsrc = hbuf + (t & 1) * (BB * HHH);
    unsigned short* hdst = hbuf + ((t + 1) & 1) * (BB * HHH);

    // ---- phase A: per-wave GEMM partials (registers only) -------------
    const unsigned short* asrc;
    if (isx) {
      asrc = xb + (size_t)t * (BB * II);   // no global wait for x-waves
    } else {
      if (t) {
        while (__hip_atomic_load(epoch, __ATOMIC_RELAXED,
                                 __HIP_MEMORY_SCOPE_AGENT) < (unsigned)t)
          __builtin_amdgcn_s_sleep(1);
        __threadfence();   // acquire: invalidate stale cached h lines
      }
      asrc = hsrc;
    }

    f32x4 acc[4][2];
#pragma unroll
    for (int m = 0; m < 4; ++m)
#pragma unroll
      for (int nt = 0; nt < 2; ++nt)
        acc[m][nt] = (f32x4){0.0f, 0.0f, 0.0f, 0.0f};

#pragma unroll
    for (int kc = 0; kc < 16; ++kc) {
      int k = koff + kc * 32 + quad * 8;
#pragma unroll
      for (int m = 0; m < 4; ++m) {
        short8 a = load_frag(asrc + (m * 16 + ln15) * 1024 + k);
        acc[m][0] = __builtin_amdgcn_mfma_f32_16x16x32_bf16(
            a, bfrag[kc][0], acc[m][0], 0, 0, 0);
        acc[m][1] = __builtin_amdgcn_mfma_f32_16x16x32_bf16(
            a, bfrag[kc][1], acc[m][1], 0, 0, 0);
      }
    }

    // ---- dump partials to LDS (D layout: row=(quad*4+p), col=ln15) ----
    // red was last read in the previous step's elementwise phase, which
    // completed before the previous __syncthreads (#2) — safe to write.
#pragma unroll
    for (int m = 0; m < 4; ++m)
#pragma unroll
      for (int nt = 0; nt < 2; ++nt)
#pragma unroll
        for (int p = 0; p < 4; ++p)
          red[wid][m * 16 + quad * 4 + p][nt * 16 + ln15] = acc[m][nt][p];

    __syncthreads();   // (#1)

    // ---- reduce 4 waves + bias, gate nonlinearities, state update -----
    float hv[2];
#pragma unroll
    for (int rr = 0; rr < 2; ++rr) {
      int r = erp * 2 + rr;
      float g[4];
#pragma unroll
      for (int q = 0; q < 4; ++q) {
        int col = q * 8 + r;
        g[q] = red[0][eb][col] + red[1][eb][col] + red[2][eb][col] +
               red[3][eb][col] + bsv[q][rr];
      }
      float ig = sigm(g[0]);
      float fg = sigm(g[1]);
      float gg = tanh_f(g[2]);
      float og = sigm(g[3]);
      float c = fg * cst[rr] + ig * gg;
      cst[rr] = c;
      hv[rr] = og * tanh_f(c);
    }
    unsigned hpack = (unsigned)f2bf(hv[0]) | ((unsigned)f2bf(hv[1]) << 16);
    *(unsigned*)(hdst + eb * HHH + hc0 + erp * 2) = hpack;

    if (t == TT - 1) {
      float2 o2; o2.x = hv[0]; o2.y = hv[1];
      *(float2*)(out + eb * HHH + hc0 + erp * 2) = o2;
    }

    __syncthreads();   // (#2) all h stores vmcnt-drained by every thread

    // ---- arrival: 2-level tree, single-writer epoch broadcast ---------
    if (t < TT - 1 && tid == 0) {
      __threadfence();   // release: flush this block's h writes device-wide
      unsigned old = atomicAdd(leaf, 1u);
      if (old == (unsigned)t * 16u + 15u) {        // last of 16 in group
        unsigned old2 = atomicAdd(root, 1u);
        if (old2 == (unsigned)t * 8u + 7u)         // last of 8 groups
          atomicExch(epoch, (unsigned)(t + 1));    // RMW: agent-visible
      }
    }
    // x-waves fall through to step t+1 immediately; h-waves poll there.
  }
}

// ---- launcher ----------------------------------------------------------
extern "C" void kernel_launch(void* const* d_in, const int* in_sizes, int n_in,
                              void* d_out, int out_size, void* d_ws,
                              size_t ws_size, hipStream_t stream) {
  (void)in_sizes; (void)n_in; (void)out_size; (void)ws_size;
  const float* x   = (const float*)d_in[0];
  const float* wih = (const float*)d_in[1];
  const float* whh = (const float*)d_in[2];
  const float* bih = (const float*)d_in[3];
  const float* bhh = (const float*)d_in[4];

  char* ws = (char*)d_ws;
  // workspace layout (bytes):
  //   [0, 4096)          barrier: epoch/root/leaf counters (128B-spaced)
  //   [4096, +256KiB)    h double buffer (2 x 64x1024 bf16)
  //   [1MiB, 9MiB)       W_ih bf16
  //   [9MiB, 17MiB)      W_hh bf16
  //   [17MiB, +16KiB)    bias sum f32
  //   [18MiB, 82MiB)     x bf16
  unsigned int*   bar  = (unsigned int*)(ws);
  unsigned short* hb   = (unsigned short*)(ws + 4096);
  unsigned short* wihb = (unsigned short*)(ws + (1ull << 20));
  unsigned short* whhb = (unsigned short*)(ws + (9ull << 20));
  float*          bs   = (float*)(ws + (17ull << 20));
  unsigned short* xb   = (unsigned short*)(ws + (18ull << 20));

  // zero barrier + h buffers (ws is poisoned 0xAA before every launch)
  hipMemsetAsync(ws, 0, 4096 + 2ull * BB * HHH * sizeof(unsigned short),
                 stream);

  cvt_bf16<<<2048, 256, 0, stream>>>(x, xb, (TT * BB * II) / 4);
  cvt_bf16<<<1024, 256, 0, stream>>>(wih, wihb, (G4 * II) / 4);
  cvt_bf16<<<1024, 256, 0, stream>>>(whh, whhb, (G4 * HHH) / 4);
  bias_sum<<<16, 256, 0, stream>>>(bih, bhh, bs);

  lstm_persist<<<NBLK, 256, 0, stream>>>(xb, wihb, whhb, bs, hb, bar,
                                         (float*)d_out);
}